// Round 11
// baseline (293.604 us; speedup 1.0000x reference)
//
#include <hip/hip_runtime.h>
#include <hip/hip_fp16.h>
#include <math.h>

// CAM_43344809951340: per-sample symmetric outer-product tanh attention.
// H_row[r] = 0.1*relu( sum_j tanh(x_r * av_j / 8) * W_{row_r}[j] + x_r )
//
// Validated diagonal walk (R5-R10, absmax ~2e-3): step k=31..1, lane r
// computes the pair (r, j=(r+k)&63) once:
//   own-row:  p * wo_k   (wo_k = W_{sel(r)}[(r+k)&63])
//   mirror:   t = ror1(fma(p, wd_k, t))  (wd_k = W_{sel(j)}[r]);
//             WAVE_ROR1 (0x13C) moves values toward higher lanes, so a
//             deposit at step k lands at lane r+k after its k rotations.
//   av operand a travels by ror1 from 32*x_{r+31} down to 32*x_{r+1}.
// tanh via 2048-pt nearest LDS table over [-4,4] (R10, validated).
//
// R11 change (from R10 counters): kernel is LATENCY-bound, not issue-bound
// (wall 3180 cy/pair vs ~1150 cy modeled VALU issue; DS ~58% busy; only
// 24 waves/CU resident, LDS-capped at 24.5 KB). Fix occupancy: pack the
// per-step weight pair {wo,wd} as __half2 -> weight table 16 KB -> 8 KB,
// total LDS ~16.4 KB -> 8 blocks/CU = 32 waves/CU (chip max), and the
// per-step weight read becomes ds_read_b32. |W|<=0.5 so f16 adds <=~5e-4
// output error (budget 1.09e-2). launch_bounds(256,8) pins VGPR<=64 --
// required for 8 waves/SIMD (R10 used 60).

__device__ __forceinline__ float wave_ror1_f32(float v) {
    // D[i] = S[(i-1) & 63] — values move toward higher lanes
    return __int_as_float(__builtin_amdgcn_update_dpp(
        __float_as_int(v), __float_as_int(v), 0x13C, 0xF, 0xF, false));
}

// tanh(x * av / 8) by nearest lookup; as = 32*av so 256*(x*av/8) = x*as.
__device__ __forceinline__ float tanh_lut(const float* __restrict__ tb,
                                          float x, float as) {
    float idxf = fmaf(x, as, 1024.5f);                 // +0.5: round via trunc
    idxf = __builtin_amdgcn_fmed3f(idxf, 0.0f, 2047.0f);
    return tb[(int)idxf];
}

__global__ __launch_bounds__(256, 8) void cam_kernel(
    const float* __restrict__ f1,
    const float* __restrict__ f2,
    const float* __restrict__ Wca,
    const float* __restrict__ Wcv,
    float* __restrict__ out,
    int B)
{
    // s_Qh[k][ln] = half2{ W_{sel(ln)}[(ln+k)&63], W_{half((ln+k)&63)}[ln] }
    __shared__ __half2 s_Qh[32][64];                   // 8 KB
    __shared__ float s_tanh[2048];                     // 8 KB

    const int tid  = threadIdx.x;
    const int lane = tid & 63;

    for (int i = tid; i < 2048; i += 256)              // tanh((i-1024)/256)
        s_tanh[i] = tanhf((float)(i - 1024) * 0.00390625f);

    for (int idx = tid; idx < 32 * 64; idx += 256) {
        const int k   = idx >> 6;
        const int ln  = idx & 63;
        const int sel = ln >> 5;
        const int j   = (ln + k) & 63;
        const float wo = (sel ? Wcv : Wca)[j];
        const float wd = ((j < 32) ? Wca : Wcv)[ln];
        s_Qh[k][ln] = __floats2half2_rn(wo, wd);
    }
    __syncthreads();

    const int sel = lane >> 5;                         // 0: audio, 1: visual
    const float* __restrict__ fbase = sel ? f2 : f1;
    const float* __restrict__ tb = s_tanh;
    const __half2* __restrict__ Qp = &s_Qh[0][lane];   // step k at Qp[k*64]
    const int col = lane & 31;

    const float w0  = (sel ? Wcv : Wca)[lane];         // k=0 (diagonal), f32 exact
    const float w32 = (sel ? Wcv : Wca)[lane ^ 32];    // k=32
    const int idx31 = ((lane + 31) & 63) << 2;         // bpermute byte indices
    const int idx32 = (lane ^ 32) << 2;

    const int gw     = (blockIdx.x * 256 + tid) >> 6;
    const int stride = (gridDim.x << 2) * 2;           // 2 samples per wave/iter

    int b = gw * 2;
    if (b >= B) return;                                // wave-uniform
    float xA = fbase[b * 32 + col];
    float xB = (b + 1 < B) ? fbase[(b + 1) * 32 + col] : 0.0f;

    while (b < B) {
        const int bn = b + stride;
        float xnA = 0.0f, xnB = 0.0f;
        if (bn < B) {                                  // prefetch next pair
            xnA = fbase[bn * 32 + col];
            if (bn + 1 < B) xnB = fbase[(bn + 1) * 32 + col];
        }

        const float xsA = xA * 32.0f;                  // 32*av contribution
        const float xsB = xB * 32.0f;
        float aA = __int_as_float(                     // 32*x_{(r+31)&63}
            __builtin_amdgcn_ds_bpermute(idx31, __float_as_int(xsA)));
        float aB = __int_as_float(
            __builtin_amdgcn_ds_bpermute(idx31, __float_as_int(xsB)));
        const float a32A = __int_as_float(             // 32*x_{r^32}
            __builtin_amdgcn_ds_bpermute(idx32, __float_as_int(xsA)));
        const float a32B = __int_as_float(
            __builtin_amdgcn_ds_bpermute(idx32, __float_as_int(xsB)));

        // k=0 diagonal + k=32 (both lanes own-row), per sample
        float own0A = tanh_lut(tb, xA, xsA)  * w0;
        float own0B = tanh_lut(tb, xB, xsB)  * w0;
        float own1A = tanh_lut(tb, xA, a32A) * w32;
        float own1B = tanh_lut(tb, xB, a32B) * w32;

        float tA = 0.0f, tB = 0.0f;                    // traveling mirror accs
        #pragma unroll
        for (int k = 31; k >= 1; --k) {
            const float2 w2 = __half22float2(Qp[k * 64]);  // ds_read_b32 + 2 cvt
            const float pA = tanh_lut(tb, xA, aA);
            const float pB = tanh_lut(tb, xB, aB);
            if (k & 1) { own0A = fmaf(pA, w2.x, own0A); own0B = fmaf(pB, w2.x, own0B); }
            else       { own1A = fmaf(pA, w2.x, own1A); own1B = fmaf(pB, w2.x, own1B); }
            tA = wave_ror1_f32(fmaf(pA, w2.y, tA));
            aA = wave_ror1_f32(aA);
            tB = wave_ror1_f32(fmaf(pB, w2.y, tB));
            aB = wave_ror1_f32(aB);
        }
        // after the k=1 iteration each deposit has had exactly k rotations

        const float hA = fmaxf(xA + own0A + own1A + tA, 0.0f) * 0.1f;
        const float hB = fmaxf(xB + own0B + own1B + tB, 0.0f) * 0.1f;
        out[b * 64 + lane] = hA;
        if (b + 1 < B) out[(b + 1) * 64 + lane] = hB;

        b = bn;
        xA = xnA;
        xB = xnB;
    }
}

extern "C" void kernel_launch(void* const* d_in, const int* in_sizes, int n_in,
                              void* d_out, int out_size, void* d_ws, size_t ws_size,
                              hipStream_t stream) {
    const float* f1  = (const float*)d_in[0];
    const float* f2  = (const float*)d_in[1];
    const float* Wca = (const float*)d_in[2];
    const float* Wcv = (const float*)d_in[3];
    float* out = (float*)d_out;

    const int B = in_sizes[0] / 32;
    const int pairs = (B + 1) / 2;
    int blocks = (pairs + 3) / 4;       // 4 waves/block, 1 pair/wave minimum
    if (blocks > 2048) blocks = 2048;   // 8 blocks/CU (16.4 KB LDS) = 32 waves/CU
    if (blocks < 1) blocks = 1;

    cam_kernel<<<blocks, 256, 0, stream>>>(f1, f2, Wca, Wcv, out, B);
}

// Round 12
// 122.618 us; speedup vs baseline: 2.3945x; 2.3945x over previous
//
#include <hip/hip_runtime.h>
#include <hip/hip_fp16.h>
#include <math.h>

// CAM_43344809951340: per-sample symmetric outer-product tanh attention.
// H_row[r] = 0.1*relu( sum_j tanh(x_r * av_j / 8) * W_{row_r}[j] + x_r )
//
// Validated diagonal walk (R5-R10, absmax ~2e-3): step k=31..1, lane r
// computes the pair (r, j=(r+k)&63) once:
//   own-row:  p * wo_k   (wo_k = W_{sel(r)}[(r+k)&63])
//   mirror:   t = ror1(fma(p, wd_k, t))  (wd_k = W_{sel(j)}[r]);
//             WAVE_ROR1 (0x13C) moves values toward higher lanes, so a
//             deposit at step k lands at lane r+k after its k rotations.
//   av operand a travels by ror1 from 32*x_{r+31} down to 32*x_{r+1}.
// tanh via 2048-pt nearest LDS table over [-4,4] (R10, validated).
// Weights packed __half2 -> 8 KB table, total LDS 16.4 KB -> 8 blocks/CU.
//
// R12 change (single variable, from the R7/R11 spill pattern):
// __launch_bounds__(256,4), NOT (256,8). The 8-waves/EU cap = 64-VGPR
// budget; whenever the body needs ~65+, regalloc spills the whole loop to
// scratch (VGPR collapses to 32, FETCH 577 MB, VALUBusy 22% -- R7/R9/R11).
// The cap was never needed: occupancy follows the ACTUAL VGPR count
// (R10: 60 VGPR under a 128 budget). With LDS at 16.4 KB and VGPR<=64 the
// HW gives 8 blocks/CU = 32 waves/CU on its own.

__device__ __forceinline__ float wave_ror1_f32(float v) {
    // D[i] = S[(i-1) & 63] — values move toward higher lanes
    return __int_as_float(__builtin_amdgcn_update_dpp(
        __float_as_int(v), __float_as_int(v), 0x13C, 0xF, 0xF, false));
}

// tanh(x * av / 8) by nearest lookup; as = 32*av so 256*(x*av/8) = x*as.
__device__ __forceinline__ float tanh_lut(const float* __restrict__ tb,
                                          float x, float as) {
    float idxf = fmaf(x, as, 1024.5f);                 // +0.5: round via trunc
    idxf = __builtin_amdgcn_fmed3f(idxf, 0.0f, 2047.0f);
    return tb[(int)idxf];
}

__global__ __launch_bounds__(256, 4) void cam_kernel(
    const float* __restrict__ f1,
    const float* __restrict__ f2,
    const float* __restrict__ Wca,
    const float* __restrict__ Wcv,
    float* __restrict__ out,
    int B)
{
    // s_Qh[k][ln] = half2{ W_{sel(ln)}[(ln+k)&63], W_{half((ln+k)&63)}[ln] }
    __shared__ __half2 s_Qh[32][64];                   // 8 KB
    __shared__ float s_tanh[2048];                     // 8 KB

    const int tid  = threadIdx.x;
    const int lane = tid & 63;

    for (int i = tid; i < 2048; i += 256)              // tanh((i-1024)/256)
        s_tanh[i] = tanhf((float)(i - 1024) * 0.00390625f);

    for (int idx = tid; idx < 32 * 64; idx += 256) {
        const int k   = idx >> 6;
        const int ln  = idx & 63;
        const int sel = ln >> 5;
        const int j   = (ln + k) & 63;
        const float wo = (sel ? Wcv : Wca)[j];
        const float wd = ((j < 32) ? Wca : Wcv)[ln];
        s_Qh[k][ln] = __floats2half2_rn(wo, wd);
    }
    __syncthreads();

    const int sel = lane >> 5;                         // 0: audio, 1: visual
    const float* __restrict__ fbase = sel ? f2 : f1;
    const float* __restrict__ tb = s_tanh;
    const __half2* __restrict__ Qp = &s_Qh[0][lane];   // step k at Qp[k*64]
    const int col = lane & 31;

    const float w0  = (sel ? Wcv : Wca)[lane];         // k=0 (diagonal), f32 exact
    const float w32 = (sel ? Wcv : Wca)[lane ^ 32];    // k=32
    const int idx31 = ((lane + 31) & 63) << 2;         // bpermute byte indices
    const int idx32 = (lane ^ 32) << 2;

    const int gw     = (blockIdx.x * 256 + tid) >> 6;
    const int stride = (gridDim.x << 2) * 2;           // 2 samples per wave/iter

    int b = gw * 2;
    if (b >= B) return;                                // wave-uniform
    float xA = fbase[b * 32 + col];
    float xB = (b + 1 < B) ? fbase[(b + 1) * 32 + col] : 0.0f;

    while (b < B) {
        const int bn = b + stride;
        float xnA = 0.0f, xnB = 0.0f;
        if (bn < B) {                                  // prefetch next pair
            xnA = fbase[bn * 32 + col];
            if (bn + 1 < B) xnB = fbase[(bn + 1) * 32 + col];
        }

        const float xsA = xA * 32.0f;                  // 32*av contribution
        const float xsB = xB * 32.0f;
        float aA = __int_as_float(                     // 32*x_{(r+31)&63}
            __builtin_amdgcn_ds_bpermute(idx31, __float_as_int(xsA)));
        float aB = __int_as_float(
            __builtin_amdgcn_ds_bpermute(idx31, __float_as_int(xsB)));
        const float a32A = __int_as_float(             // 32*x_{r^32}
            __builtin_amdgcn_ds_bpermute(idx32, __float_as_int(xsA)));
        const float a32B = __int_as_float(
            __builtin_amdgcn_ds_bpermute(idx32, __float_as_int(xsB)));

        // k=0 diagonal + k=32 (both lanes own-row), per sample
        float own0A = tanh_lut(tb, xA, xsA)  * w0;
        float own0B = tanh_lut(tb, xB, xsB)  * w0;
        float own1A = tanh_lut(tb, xA, a32A) * w32;
        float own1B = tanh_lut(tb, xB, a32B) * w32;

        float tA = 0.0f, tB = 0.0f;                    // traveling mirror accs
        #pragma unroll
        for (int k = 31; k >= 1; --k) {
            const float2 w2 = __half22float2(Qp[k * 64]);  // ds_read_b32 + 2 cvt
            const float pA = tanh_lut(tb, xA, aA);
            const float pB = tanh_lut(tb, xB, aB);
            if (k & 1) { own0A = fmaf(pA, w2.x, own0A); own0B = fmaf(pB, w2.x, own0B); }
            else       { own1A = fmaf(pA, w2.x, own1A); own1B = fmaf(pB, w2.x, own1B); }
            tA = wave_ror1_f32(fmaf(pA, w2.y, tA));
            aA = wave_ror1_f32(aA);
            tB = wave_ror1_f32(fmaf(pB, w2.y, tB));
            aB = wave_ror1_f32(aB);
        }
        // after the k=1 iteration each deposit has had exactly k rotations

        const float hA = fmaxf(xA + own0A + own1A + tA, 0.0f) * 0.1f;
        const float hB = fmaxf(xB + own0B + own1B + tB, 0.0f) * 0.1f;
        out[b * 64 + lane] = hA;
        if (b + 1 < B) out[(b + 1) * 64 + lane] = hB;

        b = bn;
        xA = xnA;
        xB = xnB;
    }
}

extern "C" void kernel_launch(void* const* d_in, const int* in_sizes, int n_in,
                              void* d_out, int out_size, void* d_ws, size_t ws_size,
                              hipStream_t stream) {
    const float* f1  = (const float*)d_in[0];
    const float* f2  = (const float*)d_in[1];
    const float* Wca = (const float*)d_in[2];
    const float* Wcv = (const float*)d_in[3];
    float* out = (float*)d_out;

    const int B = in_sizes[0] / 32;
    const int pairs = (B + 1) / 2;
    int blocks = (pairs + 3) / 4;       // 4 waves/block, 1 pair/wave minimum
    if (blocks > 2048) blocks = 2048;   // 8 blocks/CU (16.4 KB LDS) = 32 waves/CU
    if (blocks < 1) blocks = 1;

    cam_kernel<<<blocks, 256, 0, stream>>>(f1, f2, Wca, Wcv, out, B);
}